// Round 8
// baseline (211.888 us; speedup 1.0000x reference)
//
#include <hip/hip_runtime.h>
#include <hip/hip_bf16.h>
#include <math.h>

// Problem constants
#define BB    1024
#define INN   1024
#define OUTN  1024
#define NQ    10
#define GG    4
#define DEPTH 4
#define QDIM  1024   // 2^NQ
#define EPSN  1e-9f

typedef short  bf16x8 __attribute__((ext_vector_type(8)));
typedef float  f32x4  __attribute__((ext_vector_type(4)));
typedef float  f32x2  __attribute__((ext_vector_type(2)));

#define GLOAD_LDS16(gp, lp) __builtin_amdgcn_global_load_lds( \
    (__attribute__((address_space(1))) const void*)(gp),      \
    (__attribute__((address_space(3))) void*)(lp), 16, 0, 0)

__device__ __forceinline__ unsigned short f2bf(float f) {
    unsigned int u = __float_as_uint(f);
    u = (u + 0x7FFFu + ((u >> 16) & 1u)) >> 16;   // RNE, finite inputs
    return (unsigned short)u;
}
__device__ __forceinline__ float bf2f(unsigned short u) {
    return __uint_as_float(((unsigned int)u) << 16);
}

__device__ __forceinline__ f32x2 splat2(float s) { f32x2 v; v.x = s; v.y = s; return v; }
__device__ __forceinline__ f32x2 cswap(f32x2 a)  { f32x2 v; v.x = -a.y; v.y = a.x; return v; }

// DPP quad-perm xor1 / xor2 (VALU-pipe lane exchange)
template<int CTRL>
__device__ __forceinline__ float dppx(float x) {
    return __uint_as_float((unsigned)__builtin_amdgcn_update_dpp(
        0, (int)__float_as_uint(x), CTRL, 0xF, 0xF, true));
}

// complex 2x2 gate on packed (re,im) register pairs
__device__ __forceinline__ void rgate2(f32x2 (&av)[4], const float* __restrict__ m,
                                       int stride)
{
    #pragma unroll
    for (int p = 0; p < 2; ++p) {
        const int e0 = (stride == 1) ? (p << 1) : p;
        const int e1 = e0 + stride;
        f32x2 a0 = av[e0], a1 = av[e1];
        f32x2 s0 = cswap(a0), s1 = cswap(a1);
        av[e0] = splat2(m[0]) * a0 + splat2(m[1]) * s0
               + splat2(m[2]) * a1 + splat2(m[3]) * s1;
        av[e1] = splat2(m[4]) * a0 + splat2(m[5]) * s0
               + splat2(m[6]) * a1 + splat2(m[7]) * s1;
    }
}

// butterfly gate across lane-xor X, packed complex
template<int X>
__device__ __forceinline__ void bfly2(f32x2 (&av)[4], const float* __restrict__ m,
                                      int ln)
{
    const int side = (ln & X) ? 1 : 0;
    const float cr0 = side ? m[6] : m[0], ci0 = side ? m[7] : m[1];
    const float cr1 = side ? m[4] : m[2], ci1 = side ? m[5] : m[3];
    #pragma unroll
    for (int r = 0; r < 4; ++r) {
        f32x2 t;
        if (X == 1)      { t.x = dppx<0xB1>(av[r].x); t.y = dppx<0xB1>(av[r].y); }
        else if (X == 2) { t.x = dppx<0x4E>(av[r].x); t.y = dppx<0x4E>(av[r].y); }
        else             { t.x = __shfl_xor(av[r].x, X, 64);
                           t.y = __shfl_xor(av[r].y, X, 64); }
        av[r] = splat2(cr0) * av[r] + splat2(ci0) * cswap(av[r])
              + splat2(cr1) * t     + splat2(ci1) * cswap(t);
    }
}

// ---------------------------------------------------------------------------
// Fused prep: [0,512): xsb = bf16(x*sc); [512,2560): wb1 = bf16(proj_in_w);
// [2560,4608): wb2 = bf16(proj_out_w); [4608,5632): reup angles.
// ---------------------------------------------------------------------------
__global__ __launch_bounds__(256) void prep_kernel(
    const float* __restrict__ x, const float* __restrict__ sc,
    const float* __restrict__ piw, const float* __restrict__ pow_,
    const float* __restrict__ rw, const float* __restrict__ rb,
    unsigned short* __restrict__ xsb, unsigned short* __restrict__ wb1,
    unsigned short* __restrict__ wb2, float* __restrict__ ang)
{
    const int bid = blockIdx.x;
    if (bid < 4608) {
        const float* src; unsigned short* dst; int i; bool scale = false;
        if (bid < 512)        { src = x;    dst = xsb; i = bid * 256 + threadIdx.x; scale = true; }
        else if (bid < 2560)  { src = piw;  dst = wb1; i = (bid - 512) * 256 + threadIdx.x; }
        else                  { src = pow_; dst = wb2; i = (bid - 2560) * 256 + threadIdx.x; }
        float4 a = ((const float4*)src)[2 * i];
        float4 b = ((const float4*)src)[2 * i + 1];
        if (scale) {
            int c4 = (2 * i) & 255;
            float4 s0 = ((const float4*)sc)[c4];
            float4 s1 = ((const float4*)sc)[c4 + 1];
            a.x *= s0.x; a.y *= s0.y; a.z *= s0.z; a.w *= s0.w;
            b.x *= s1.x; b.y *= s1.y; b.z *= s1.z; b.w *= s1.w;
        }
        ushort4 o0, o1;
        o0.x = f2bf(a.x); o0.y = f2bf(a.y); o0.z = f2bf(a.z); o0.w = f2bf(a.w);
        o1.x = f2bf(b.x); o1.y = f2bf(b.y); o1.z = f2bf(b.z); o1.w = f2bf(b.w);
        ((ushort4*)dst)[2 * i]     = o0;
        ((ushort4*)dst)[2 * i + 1] = o1;
    } else {
        const int b = bid - 4608;
        const int lane = threadIdx.x & 63;
        const int wv = threadIdx.x >> 6;
        const float* xrow = x + (size_t)b * INN;
        float xr[16];
        #pragma unroll
        for (int t = 0; t < 16; ++t) xr[t] = xrow[lane + 64 * t] * sc[lane + 64 * t];
        for (int j = wv; j < NQ * GG; j += 4) {
            const float* wrow = rw + (size_t)j * INN;
            float s = 0.f;
            #pragma unroll
            for (int t = 0; t < 16; ++t) s += xr[t] * wrow[lane + 64 * t];
            #pragma unroll
            for (int off = 32; off; off >>= 1) s += __shfl_xor(s, off, 64);
            if (lane == 0) {
                float a = tanhf(s + rb[j]) * 3.14159265358979323846f;
                int g = j / NQ, i = j % NQ;
                ang[((size_t)b * GG + g) * NQ + i] = a;
            }
        }
    }
}

// ---------------------------------------------------------------------------
// bf16 MFMA GEMM (R6 config — best so far): 256 threads = 4 waves (2x2),
// BK=128, XOR-swizzled LDS (linear dest + pre-swizzled global source).
// Split-K via blockIdx.z; fp32 partials at hole offsets.
// ---------------------------------------------------------------------------
template<int BM, int BN, int BK, bool OUTBF>
__global__ __launch_bounds__(256) void gemm_bt_bf16(
    const unsigned short* __restrict__ A, const unsigned short* __restrict__ Bw,
    const float* __restrict__ bias, void* __restrict__ Cv,
    int M, int N, int K, int KC)
{
    static_assert(BK == 128, "swizzle assumes BK=128");
    constexpr int WM = BM / 2, WN = BN / 2;
    constexpr int FM = WM / 16, FN = WN / 16;
    constexpr int KS = BK / 32;
    constexpr int NA = (BM * BK) / 2048;
    constexpr int NB = (BN * BK) / 2048;

    __shared__ unsigned short As[BM * BK];
    __shared__ unsigned short Bs[BN * BK];

    const int tid  = threadIdx.x;
    const int lane = tid & 63;
    const int wave = tid >> 6;
    const int wm = wave >> 1, wn = wave & 1;
    const int m0 = blockIdx.y * BM;
    const int n0 = blockIdx.x * BN;
    const int k0 = blockIdx.z * KC;

    const int cl = lane & 15;
    const int rh = lane >> 4;

    f32x4 acc[FM][FN];
    #pragma unroll
    for (int i = 0; i < FM; ++i)
        #pragma unroll
        for (int j = 0; j < FN; ++j)
            acc[i][j] = (f32x4){0.f, 0.f, 0.f, 0.f};

    for (int kt = k0; kt < k0 + KC; kt += BK) {
        #pragma unroll
        for (int q = 0; q < NA; ++q) {
            int eo  = q * 2048 + tid * 8;
            int row = eo >> 7;
            int pb  = (eo & 127) >> 3;
            int gb  = pb ^ (row & 7);
            GLOAD_LDS16(A + (size_t)(m0 + row) * K + kt + gb * 8, &As[eo]);
        }
        #pragma unroll
        for (int q = 0; q < NB; ++q) {
            int eo  = q * 2048 + tid * 8;
            int row = eo >> 7;
            int pb  = (eo & 127) >> 3;
            int gb  = pb ^ (row & 7);
            GLOAD_LDS16(Bw + (size_t)(n0 + row) * K + kt + gb * 8, &Bs[eo]);
        }
        __syncthreads();

        #pragma unroll
        for (int ks = 0; ks < KS; ++ks) {
            bf16x8 af[FM], bfr[FN];
            #pragma unroll
            for (int mi = 0; mi < FM; ++mi) {
                int row = wm * WM + mi * 16 + cl;
                int pb  = (ks * 4 + rh) ^ (row & 7);
                af[mi] = *(const bf16x8*)&As[row * BK + pb * 8];
            }
            #pragma unroll
            for (int ni = 0; ni < FN; ++ni) {
                int row = wn * WN + ni * 16 + cl;
                int pb  = (ks * 4 + rh) ^ (row & 7);
                bfr[ni] = *(const bf16x8*)&Bs[row * BK + pb * 8];
            }
            #pragma unroll
            for (int mi = 0; mi < FM; ++mi)
                #pragma unroll
                for (int ni = 0; ni < FN; ++ni)
                    acc[mi][ni] = __builtin_amdgcn_mfma_f32_16x16x32_bf16(
                        af[mi], bfr[ni], acc[mi][ni], 0, 0, 0);
        }
        __syncthreads();
    }

    // epilogue: C/D layout col=lane&15, row=(lane>>4)*4+j
    const size_t pofs = OUTBF ? 0 :
        ((size_t)(blockIdx.z & 1) + ((size_t)(blockIdx.z >> 1) << 2)) * ((size_t)M * N);
    #pragma unroll
    for (int mi = 0; mi < FM; ++mi) {
        #pragma unroll
        for (int ni = 0; ni < FN; ++ni) {
            int gm = m0 + wm * WM + mi * 16 + rh * 4;
            int gn = n0 + wn * WN + ni * 16 + cl;
            float bsv = bias ? bias[gn] : 0.f;
            #pragma unroll
            for (int j = 0; j < 4; ++j) {
                float val = acc[mi][ni][j] + bsv;
                if (OUTBF)
                    ((unsigned short*)Cv)[(size_t)(gm + j) * N + gn] = f2bf(val);
                else
                    ((float*)Cv)[pofs + (size_t)(gm + j) * N + gn] = val;
            }
        }
    }
}

// out = p0 + p1 + p2 + p3 + bias; partials at float4 offsets 0, 1<<18, 1<<20, (1<<20)+(1<<18)
__global__ __launch_bounds__(256) void reduce4_kernel(
    const float* __restrict__ p, const float* __restrict__ bias,
    float* __restrict__ out)
{
    int i = blockIdx.x * 256 + threadIdx.x;           // float4 index, 262144
    float4 a = ((const float4*)p)[i];
    float4 b = ((const float4*)p)[i + (1 << 18)];
    float4 c = ((const float4*)p)[i + (1 << 20)];
    float4 d = ((const float4*)p)[i + (1 << 20) + (1 << 18)];
    float4 bv = ((const float4*)bias)[i & 255];
    float4 o;
    o.x = a.x + b.x + c.x + d.x + bv.x;
    o.y = a.y + b.y + c.y + d.y + bv.y;
    o.z = a.z + b.z + c.z + d.z + bv.z;
    o.w = a.w + b.w + c.w + d.w + bv.w;
    ((float4*)out)[i] = o;
}

// ---------------------------------------------------------------------------
// Quantum statevector sim, register-resident, packed-complex (f32x2 → v_pk_*).
// Amp bits: [9:8]=wave, [7:2]=lane, [1:0]=reg slot. 4 amps/thread.
// ---------------------------------------------------------------------------
__global__ __launch_bounds__(256) void quantum_kernel(
    const unsigned short* __restrict__ xqb, const float* __restrict__ ang,
    const float* __restrict__ qw, const float* __restrict__ us,
    const float* __restrict__ mw, unsigned short* __restrict__ probs)
{
    __shared__ float2 bufA[QDIM];
    __shared__ float2 bufB[QDIM];
    __shared__ float lmat[DEPTH + 1][NQ][8];
    __shared__ float red[4];

    const int tid = threadIdx.x;
    const int wv  = tid >> 6;
    const int ln  = tid & 63;
    const int wid = blockIdx.x;          // b*G+g
    const int g   = wid & 3;

    // ---- build all 50 fused gate matrices ----
    if (tid < (DEPTH + 1) * NQ) {
        const int l = tid / NQ;
        const int i = tid - l * NQ;
        float carry = 0.f;
        if (l > 0) {
            int pl = (l == DEPTH) ? DEPTH - 1 : l - 1;
            carry = qw[(((size_t)g * DEPTH + pl) * NQ + i) * 3 + 2];
        }
        float m0r,m0i,m1r,m1i,m2r,m2i,m3r,m3i;
        if (l < DEPTH) {
            int idx = (g * DEPTH + l) * NQ + i;
            float q0 = qw[(size_t)idx * 3 + 0], q1 = qw[(size_t)idx * 3 + 1];
            float beta = ang[(size_t)wid * NQ + i] * us[idx] + carry;
            float s0 = sinf(0.5f * q0), c0 = cosf(0.5f * q0);
            float s1 = sinf(0.5f * q1), c1 = cosf(0.5f * q1);
            float p0r =  c1 * c0, p0i =  s1 * s0;
            float p1r = -s1 * c0, p1i = -c1 * s0;
            float p2r =  s1 * c0, p2i = -c1 * s0;
            float p3r =  c1 * c0, p3i = -s1 * s0;
            float cb = cosf(0.5f * beta), sb = sinf(0.5f * beta);
            m0r = p0r*cb + p1r*sb;  m0i = p0i*cb + p1i*sb;
            m1r = p1r*cb - p0r*sb;  m1i = p1i*cb - p0i*sb;
            m2r = p2r*cb + p3r*sb;  m2i = p2i*cb + p3i*sb;
            m3r = p3r*cb - p2r*sb;  m3i = p3i*cb - p2i*sb;
        } else {
            const float* q = mw + ((size_t)g * NQ + i) * 3;
            float th = q[0], ph = q[1], lm_ = q[2];
            float c = cosf(0.5f * th), s = sinf(0.5f * th);
            float epr = cosf(ph), epi = sinf(ph);
            float elr = cosf(lm_), eli = sinf(lm_);
            float u0r = c,        u0i = 0.f;
            float u1r = -elr * s, u1i = -eli * s;
            float u2r = epr * s,  u2i = epi * s;
            float u3r = (epr*elr - epi*eli) * c;
            float u3i = (epr*eli + epi*elr) * c;
            float cc = cosf(0.5f * carry), sc2 = sinf(0.5f * carry);
            m0r = u0r*cc + u1r*sc2;  m0i = u0i*cc + u1i*sc2;
            m1r = u1r*cc - u0r*sc2;  m1i = u1i*cc - u0i*sc2;
            m2r = u2r*cc + u3r*sc2;  m2i = u2i*cc + u3i*sc2;
            m3r = u3r*cc - u2r*sc2;  m3i = u3i*cc - u2i*sc2;
        }
        float* m = lmat[l][i];
        m[0]=m0r; m[1]=m0i; m[2]=m1r; m[3]=m1i;
        m[4]=m2r; m[5]=m2i; m[6]=m3r; m[7]=m3i;
    }

    // ---- load own 4 amps (bf16), block-wide norm ----
    f32x2 av[4];
    {
        ushort4 uv = ((const ushort4*)xqb)[(size_t)wid * 256 + tid];
        av[0].x = bf2f(uv.x); av[1].x = bf2f(uv.y);
        av[2].x = bf2f(uv.z); av[3].x = bf2f(uv.w);
        av[0].y = 0.f; av[1].y = 0.f; av[2].y = 0.f; av[3].y = 0.f;
    }
    float ss = av[0].x*av[0].x + av[1].x*av[1].x + av[2].x*av[2].x + av[3].x*av[3].x;
    #pragma unroll
    for (int off = 32; off; off >>= 1) ss += __shfl_xor(ss, off, 64);
    if (ln == 0) red[wv] = ss;
    __syncthreads();     // also covers lmat writes
    {
        float scl = 1.f / (sqrtf(red[0] + red[1] + red[2] + red[3]) + EPSN);
        #pragma unroll
        for (int r = 0; r < 4; ++r) av[r].x *= scl;
    }

    auto lo_gates = [&](const float (*M)[8]) {
        rgate2(av, M[9], 1);
        rgate2(av, M[8], 2);
        bfly2<1>(av, M[7], ln);
        bfly2<2>(av, M[6], ln);
        bfly2<4>(av, M[5], ln);
        bfly2<8>(av, M[4], ln);
        bfly2<16>(av, M[3], ln);
        bfly2<32>(av, M[2], ln);
    };
    auto hi_gates = [&](const float (*M)[8]) {
        #pragma unroll
        for (int s = 0; s < 4; ++s) {
            int a = (wv << 8) | (ln << 2) | s;
            bufA[a ^ ((a >> 4) & 0xF)] = make_float2(av[s].x, av[s].y);
        }
        __syncthreads();
        #pragma unroll
        for (int s = 0; s < 4; ++s) {
            int a = (s << 8) | (ln << 2) | wv;
            float2 v = bufA[a ^ ((a >> 4) & 0xF)];
            av[s].x = v.x; av[s].y = v.y;
        }
        rgate2(av, M[1], 1);
        rgate2(av, M[0], 2);
    };
    auto perm_back = [&]() {
        #pragma unroll
        for (int s = 0; s < 4; ++s) {
            int a = (s << 8) | (ln << 2) | wv;
            bufB[a ^ ((a >> 5) & 0xF)] = make_float2(av[s].x, av[s].y);
        }
        __syncthreads();
        #pragma unroll
        for (int s = 0; s < 4; ++s) {
            int j = (wv << 8) | (ln << 2) | s;
            int k = (j ^ (j >> 1)) ^ ((j & 1) ? 0x300 : 0);
            float2 v = bufB[k ^ ((k >> 5) & 0xF)];
            av[s].x = v.x; av[s].y = v.y;
        }
    };

    #pragma unroll
    for (int l = 0; l < DEPTH; ++l) {
        lo_gates(lmat[l]);
        hi_gates(lmat[l]);
        perm_back();
    }
    lo_gates(lmat[DEPTH]);
    hi_gates(lmat[DEPTH]);

    // ---- probs: square in transposed layout, LDS pass back to standard ----
    #pragma unroll
    for (int s = 0; s < 4; ++s) {
        int a = (s << 8) | (ln << 2) | wv;
        bufB[a ^ ((a >> 5) & 0xF)].x = av[s].x*av[s].x + av[s].y*av[s].y;
    }
    __syncthreads();
    {
        ushort4 o;
        int j0 = tid << 2;
        int a0 = (j0 + 0), a1 = (j0 + 1), a2 = (j0 + 2), a3 = (j0 + 3);
        o.x = f2bf(bufB[a0 ^ ((a0 >> 5) & 0xF)].x);
        o.y = f2bf(bufB[a1 ^ ((a1 >> 5) & 0xF)].x);
        o.z = f2bf(bufB[a2 ^ ((a2 >> 5) & 0xF)].x);
        o.w = f2bf(bufB[a3 ^ ((a3 >> 5) & 0xF)].x);
        ((ushort4*)(probs + (size_t)wid * QDIM))[tid] = o;
    }
}

// ---------------------------------------------------------------------------
// ws layout (stream-ordered reuse):
//   [ 0, 8)MB : xqb (gemm1 out, quantum in)  -> cpart z=0@0MB, z=1@4MB
//   [ 8,16)MB : probsb (quantum out, gemm2 A)
//   [16,24)MB : wb1 (gemm1 B, dead after)    -> cpart z=2@16MB, z=3@20MB
//   [24,32)MB : wb2 (gemm2 B)
//   [32,34)MB : xsb ; 34MB+: angb
// ---------------------------------------------------------------------------
extern "C" void kernel_launch(void* const* d_in, const int* in_sizes, int n_in,
                              void* d_out, int out_size, void* d_ws, size_t ws_size,
                              hipStream_t stream)
{
    const float* x          = (const float*)d_in[0];
    const float* inp_scale  = (const float*)d_in[1];
    const float* proj_in_w  = (const float*)d_in[2];
    const float* proj_in_b  = (const float*)d_in[3];
    const float* reup_w     = (const float*)d_in[4];
    const float* reup_b     = (const float*)d_in[5];
    const float* q_weights  = (const float*)d_in[6];
    const float* upl_scales = (const float*)d_in[7];
    const float* meas_w     = (const float*)d_in[8];
    const float* proj_out_w = (const float*)d_in[9];
    const float* proj_out_b = (const float*)d_in[10];
    float* out = (float*)d_out;

    char* ws = (char*)d_ws;
    unsigned short* xqb    = (unsigned short*)ws;
    float*          cpart  = (float*)ws;
    unsigned short* probsb = (unsigned short*)(ws + ((size_t) 8 << 20));
    unsigned short* wb1    = (unsigned short*)(ws + ((size_t)16 << 20));
    unsigned short* wb2    = (unsigned short*)(ws + ((size_t)24 << 20));
    unsigned short* xsb    = (unsigned short*)(ws + ((size_t)32 << 20));
    float*          angb   = (float*)(ws + ((size_t)34 << 20));

    // casts + reup in one launch
    prep_kernel<<<5632, 256, 0, stream>>>(x, inp_scale, proj_in_w, proj_out_w,
                                          reup_w, reup_b, xsb, wb1, wb2, angb);
    // xq(bf16) = xsb @ wb1^T + b   (1024 x 4096 x 1024), BK=128  [R6 config]
    gemm_bt_bf16<64, 128, 128, true><<<dim3(32, 16, 1), 256, 0, stream>>>(
        xsb, wb1, proj_in_b, xqb, BB, GG * QDIM, INN, INN);
    // quantum sim -> probs (bf16), packed-complex
    quantum_kernel<<<BB * GG, 256, 0, stream>>>(xqb, angb, q_weights,
                                                upl_scales, meas_w, probsb);
    // partial[z] = probs @ wb2^T  (split-K=4: 1024 x 1024 x 1024 each) [R6 config]
    gemm_bt_bf16<64, 64, 128, false><<<dim3(16, 16, 4), 256, 0, stream>>>(
        probsb, wb2, nullptr, cpart, BB, OUTN, GG * QDIM, GG * QDIM / 4);
    // out = sum partials + bias
    reduce4_kernel<<<1024, 256, 0, stream>>>(cpart, proj_out_b, out);
}

// Round 9
// 204.454 us; speedup vs baseline: 1.0364x; 1.0364x over previous
//
#include <hip/hip_runtime.h>
#include <hip/hip_bf16.h>
#include <math.h>

// Problem constants
#define BB    1024
#define INN   1024
#define OUTN  1024
#define NQ    10
#define GG    4
#define DEPTH 4
#define QDIM  1024   // 2^NQ
#define EPSN  1e-9f

typedef short  bf16x8 __attribute__((ext_vector_type(8)));
typedef float  f32x4  __attribute__((ext_vector_type(4)));

#define GLOAD_LDS16(gp, lp) __builtin_amdgcn_global_load_lds( \
    (__attribute__((address_space(1))) const void*)(gp),      \
    (__attribute__((address_space(3))) void*)(lp), 16, 0, 0)

__device__ __forceinline__ unsigned short f2bf(float f) {
    unsigned int u = __float_as_uint(f);
    u = (u + 0x7FFFu + ((u >> 16) & 1u)) >> 16;   // RNE, finite inputs
    return (unsigned short)u;
}
__device__ __forceinline__ float bf2f(unsigned short u) {
    return __uint_as_float(((unsigned int)u) << 16);
}

// DPP quad-perm xor1 / xor2 (VALU-pipe lane exchange)
template<int CTRL>
__device__ __forceinline__ float dppx(float x) {
    return __uint_as_float((unsigned)__builtin_amdgcn_update_dpp(
        0, (int)__float_as_uint(x), CTRL, 0xF, 0xF, true));
}

// complex 2x2 gate on register pairs
__device__ __forceinline__ void rgate(float (&ar)[4], float (&ai)[4],
                                      const float* __restrict__ m, int stride)
{
    #pragma unroll
    for (int p = 0; p < 2; ++p) {
        const int e0 = (stride == 1) ? (p << 1) : p;
        const int e1 = e0 + stride;
        float a0r = ar[e0], a0i = ai[e0], a1r = ar[e1], a1i = ai[e1];
        ar[e0] = m[0]*a0r - m[1]*a0i + m[2]*a1r - m[3]*a1i;
        ai[e0] = m[0]*a0i + m[1]*a0r + m[2]*a1i + m[3]*a1r;
        ar[e1] = m[4]*a0r - m[5]*a0i + m[6]*a1r - m[7]*a1i;
        ai[e1] = m[4]*a0i + m[5]*a0r + m[6]*a1i + m[7]*a1r;
    }
}

// butterfly gate across lane-xor X
template<int X>
__device__ __forceinline__ void bfly(float (&ar)[4], float (&ai)[4],
                                     const float* __restrict__ m, int ln)
{
    const int side = (ln & X) ? 1 : 0;
    const float cAr = side ? m[6] : m[0], cAi = side ? m[7] : m[1];
    const float cBr = side ? m[4] : m[2], cBi = side ? m[5] : m[3];
    #pragma unroll
    for (int r = 0; r < 4; ++r) {
        float tr, ti;
        if (X == 1)      { tr = dppx<0xB1>(ar[r]); ti = dppx<0xB1>(ai[r]); }
        else if (X == 2) { tr = dppx<0x4E>(ar[r]); ti = dppx<0x4E>(ai[r]); }
        else             { tr = __shfl_xor(ar[r], X, 64); ti = __shfl_xor(ai[r], X, 64); }
        float nr = cAr*ar[r] - cAi*ai[r] + cBr*tr - cBi*ti;
        float ni = cAr*ai[r] + cAi*ar[r] + cBr*ti + cBi*tr;
        ar[r] = nr; ai[r] = ni;
    }
}

// ---------------------------------------------------------------------------
// Fused prep: [0,512): xsb = bf16(x*sc); [512,2560): wb1 = bf16(proj_in_w);
// [2560,4608): wb2 = bf16(proj_out_w); [4608,5632): reup angles.
// ---------------------------------------------------------------------------
__global__ __launch_bounds__(256) void prep_kernel(
    const float* __restrict__ x, const float* __restrict__ sc,
    const float* __restrict__ piw, const float* __restrict__ pow_,
    const float* __restrict__ rw, const float* __restrict__ rb,
    unsigned short* __restrict__ xsb, unsigned short* __restrict__ wb1,
    unsigned short* __restrict__ wb2, float* __restrict__ ang)
{
    const int bid = blockIdx.x;
    if (bid < 4608) {
        const float* src; unsigned short* dst; int i; bool scale = false;
        if (bid < 512)        { src = x;    dst = xsb; i = bid * 256 + threadIdx.x; scale = true; }
        else if (bid < 2560)  { src = piw;  dst = wb1; i = (bid - 512) * 256 + threadIdx.x; }
        else                  { src = pow_; dst = wb2; i = (bid - 2560) * 256 + threadIdx.x; }
        float4 a = ((const float4*)src)[2 * i];
        float4 b = ((const float4*)src)[2 * i + 1];
        if (scale) {
            int c4 = (2 * i) & 255;
            float4 s0 = ((const float4*)sc)[c4];
            float4 s1 = ((const float4*)sc)[c4 + 1];
            a.x *= s0.x; a.y *= s0.y; a.z *= s0.z; a.w *= s0.w;
            b.x *= s1.x; b.y *= s1.y; b.z *= s1.z; b.w *= s1.w;
        }
        ushort4 o0, o1;
        o0.x = f2bf(a.x); o0.y = f2bf(a.y); o0.z = f2bf(a.z); o0.w = f2bf(a.w);
        o1.x = f2bf(b.x); o1.y = f2bf(b.y); o1.z = f2bf(b.z); o1.w = f2bf(b.w);
        ((ushort4*)dst)[2 * i]     = o0;
        ((ushort4*)dst)[2 * i + 1] = o1;
    } else {
        const int b = bid - 4608;
        const int lane = threadIdx.x & 63;
        const int wv = threadIdx.x >> 6;
        const float* xrow = x + (size_t)b * INN;
        float xr[16];
        #pragma unroll
        for (int t = 0; t < 16; ++t) xr[t] = xrow[lane + 64 * t] * sc[lane + 64 * t];
        for (int j = wv; j < NQ * GG; j += 4) {
            const float* wrow = rw + (size_t)j * INN;
            float s = 0.f;
            #pragma unroll
            for (int t = 0; t < 16; ++t) s += xr[t] * wrow[lane + 64 * t];
            #pragma unroll
            for (int off = 32; off; off >>= 1) s += __shfl_xor(s, off, 64);
            if (lane == 0) {
                float a = tanhf(s + rb[j]) * 3.14159265358979323846f;
                int g = j / NQ, i = j % NQ;
                ang[((size_t)b * GG + g) * NQ + i] = a;
            }
        }
    }
}

// ---------------------------------------------------------------------------
// bf16 MFMA GEMM: 256 threads = 4 waves (2x2), BK=128, XOR-swizzled LDS
// (linear dest + pre-swizzled global source). Bijective XCD-aware block
// swizzle (T1): chunks of nwg/8 consecutive y-fastest tiles per XCD so
// shared B-panels stay L2-resident. Split-K via z; fp32 partials at holes.
// ---------------------------------------------------------------------------
template<int BM, int BN, int BK, bool OUTBF>
__global__ __launch_bounds__(256) void gemm_bt_bf16(
    const unsigned short* __restrict__ A, const unsigned short* __restrict__ Bw,
    const float* __restrict__ bias, void* __restrict__ Cv,
    int M, int N, int K, int KC)
{
    static_assert(BK == 128, "swizzle assumes BK=128");
    constexpr int WM = BM / 2, WN = BN / 2;
    constexpr int FM = WM / 16, FN = WN / 16;
    constexpr int KS = BK / 32;
    constexpr int NA = (BM * BK) / 2048;
    constexpr int NB = (BN * BK) / 2048;

    __shared__ unsigned short As[BM * BK];
    __shared__ unsigned short Bs[BN * BK];

    // XCD-aware bijective remap (requires nwg % 8 == 0; both launches are 512)
    const int nx = gridDim.x, ny = gridDim.y;
    const int nwg = nx * ny * gridDim.z;
    const int lin = blockIdx.x + nx * (blockIdx.y + ny * blockIdx.z);
    const int nl  = (lin & 7) * (nwg >> 3) + (lin >> 3);
    const int by  = nl % ny;
    const int bx  = (nl / ny) % nx;
    const int bz  = nl / (ny * nx);

    const int tid  = threadIdx.x;
    const int lane = tid & 63;
    const int wave = tid >> 6;
    const int wm = wave >> 1, wn = wave & 1;
    const int m0 = by * BM;
    const int n0 = bx * BN;
    const int k0 = bz * KC;

    const int cl = lane & 15;
    const int rh = lane >> 4;

    f32x4 acc[FM][FN];
    #pragma unroll
    for (int i = 0; i < FM; ++i)
        #pragma unroll
        for (int j = 0; j < FN; ++j)
            acc[i][j] = (f32x4){0.f, 0.f, 0.f, 0.f};

    for (int kt = k0; kt < k0 + KC; kt += BK) {
        #pragma unroll
        for (int q = 0; q < NA; ++q) {
            int eo  = q * 2048 + tid * 8;
            int row = eo >> 7;
            int pb  = (eo & 127) >> 3;
            int gb  = pb ^ (row & 7);
            GLOAD_LDS16(A + (size_t)(m0 + row) * K + kt + gb * 8, &As[eo]);
        }
        #pragma unroll
        for (int q = 0; q < NB; ++q) {
            int eo  = q * 2048 + tid * 8;
            int row = eo >> 7;
            int pb  = (eo & 127) >> 3;
            int gb  = pb ^ (row & 7);
            GLOAD_LDS16(Bw + (size_t)(n0 + row) * K + kt + gb * 8, &Bs[eo]);
        }
        __syncthreads();

        #pragma unroll
        for (int ks = 0; ks < KS; ++ks) {
            bf16x8 af[FM], bfr[FN];
            #pragma unroll
            for (int mi = 0; mi < FM; ++mi) {
                int row = wm * WM + mi * 16 + cl;
                int pb  = (ks * 4 + rh) ^ (row & 7);
                af[mi] = *(const bf16x8*)&As[row * BK + pb * 8];
            }
            #pragma unroll
            for (int ni = 0; ni < FN; ++ni) {
                int row = wn * WN + ni * 16 + cl;
                int pb  = (ks * 4 + rh) ^ (row & 7);
                bfr[ni] = *(const bf16x8*)&Bs[row * BK + pb * 8];
            }
            #pragma unroll
            for (int mi = 0; mi < FM; ++mi)
                #pragma unroll
                for (int ni = 0; ni < FN; ++ni)
                    acc[mi][ni] = __builtin_amdgcn_mfma_f32_16x16x32_bf16(
                        af[mi], bfr[ni], acc[mi][ni], 0, 0, 0);
        }
        __syncthreads();
    }

    // epilogue: C/D layout col=lane&15, row=(lane>>4)*4+j
    const size_t pofs = OUTBF ? 0 :
        ((size_t)(bz & 1) + ((size_t)(bz >> 1) << 2)) * ((size_t)M * N);
    #pragma unroll
    for (int mi = 0; mi < FM; ++mi) {
        #pragma unroll
        for (int ni = 0; ni < FN; ++ni) {
            int gm = m0 + wm * WM + mi * 16 + rh * 4;
            int gn = n0 + wn * WN + ni * 16 + cl;
            float bsv = bias ? bias[gn] : 0.f;
            #pragma unroll
            for (int j = 0; j < 4; ++j) {
                float val = acc[mi][ni][j] + bsv;
                if (OUTBF)
                    ((unsigned short*)Cv)[(size_t)(gm + j) * N + gn] = f2bf(val);
                else
                    ((float*)Cv)[pofs + (size_t)(gm + j) * N + gn] = val;
            }
        }
    }
}

// out = p0 + p1 + p2 + p3 + bias; partials at float4 offsets 0, 1<<18, 1<<20, (1<<20)+(1<<18)
__global__ __launch_bounds__(256) void reduce4_kernel(
    const float* __restrict__ p, const float* __restrict__ bias,
    float* __restrict__ out)
{
    int i = blockIdx.x * 256 + threadIdx.x;           // float4 index, 262144
    float4 a = ((const float4*)p)[i];
    float4 b = ((const float4*)p)[i + (1 << 18)];
    float4 c = ((const float4*)p)[i + (1 << 20)];
    float4 d = ((const float4*)p)[i + (1 << 20) + (1 << 18)];
    float4 bv = ((const float4*)bias)[i & 255];
    float4 o;
    o.x = a.x + b.x + c.x + d.x + bv.x;
    o.y = a.y + b.y + c.y + d.y + bv.y;
    o.z = a.z + b.z + c.z + d.z + bv.z;
    o.w = a.w + b.w + c.w + d.w + bv.w;
    ((float4*)out)[i] = o;
}

// ---------------------------------------------------------------------------
// Quantum statevector sim, register-resident (R6 scalar version — proven 70us).
// Amp bits: [9:8]=wave, [7:2]=lane, [1:0]=reg slot. 4 amps/thread.
// ---------------------------------------------------------------------------
__global__ __launch_bounds__(256) void quantum_kernel(
    const unsigned short* __restrict__ xqb, const float* __restrict__ ang,
    const float* __restrict__ qw, const float* __restrict__ us,
    const float* __restrict__ mw, unsigned short* __restrict__ probs)
{
    __shared__ float2 bufA[QDIM];
    __shared__ float2 bufB[QDIM];
    __shared__ float lmat[DEPTH + 1][NQ][8];
    __shared__ float red[4];

    const int tid = threadIdx.x;
    const int wv  = tid >> 6;
    const int ln  = tid & 63;
    const int wid = blockIdx.x;          // b*G+g
    const int g   = wid & 3;

    if (tid < (DEPTH + 1) * NQ) {
        const int l = tid / NQ;
        const int i = tid - l * NQ;
        float carry = 0.f;
        if (l > 0) {
            int pl = (l == DEPTH) ? DEPTH - 1 : l - 1;
            carry = qw[(((size_t)g * DEPTH + pl) * NQ + i) * 3 + 2];
        }
        float m0r,m0i,m1r,m1i,m2r,m2i,m3r,m3i;
        if (l < DEPTH) {
            int idx = (g * DEPTH + l) * NQ + i;
            float q0 = qw[(size_t)idx * 3 + 0], q1 = qw[(size_t)idx * 3 + 1];
            float beta = ang[(size_t)wid * NQ + i] * us[idx] + carry;
            float s0 = sinf(0.5f * q0), c0 = cosf(0.5f * q0);
            float s1 = sinf(0.5f * q1), c1 = cosf(0.5f * q1);
            float p0r =  c1 * c0, p0i =  s1 * s0;
            float p1r = -s1 * c0, p1i = -c1 * s0;
            float p2r =  s1 * c0, p2i = -c1 * s0;
            float p3r =  c1 * c0, p3i = -s1 * s0;
            float cb = cosf(0.5f * beta), sb = sinf(0.5f * beta);
            m0r = p0r*cb + p1r*sb;  m0i = p0i*cb + p1i*sb;
            m1r = p1r*cb - p0r*sb;  m1i = p1i*cb - p0i*sb;
            m2r = p2r*cb + p3r*sb;  m2i = p2i*cb + p3i*sb;
            m3r = p3r*cb - p2r*sb;  m3i = p3i*cb - p2i*sb;
        } else {
            const float* q = mw + ((size_t)g * NQ + i) * 3;
            float th = q[0], ph = q[1], lm_ = q[2];
            float c = cosf(0.5f * th), s = sinf(0.5f * th);
            float epr = cosf(ph), epi = sinf(ph);
            float elr = cosf(lm_), eli = sinf(lm_);
            float u0r = c,        u0i = 0.f;
            float u1r = -elr * s, u1i = -eli * s;
            float u2r = epr * s,  u2i = epi * s;
            float u3r = (epr*elr - epi*eli) * c;
            float u3i = (epr*eli + epi*elr) * c;
            float cc = cosf(0.5f * carry), sc2 = sinf(0.5f * carry);
            m0r = u0r*cc + u1r*sc2;  m0i = u0i*cc + u1i*sc2;
            m1r = u1r*cc - u0r*sc2;  m1i = u1i*cc - u0i*sc2;
            m2r = u2r*cc + u3r*sc2;  m2i = u2i*cc + u3i*sc2;
            m3r = u3r*cc - u2r*sc2;  m3i = u3i*cc - u2i*sc2;
        }
        float* m = lmat[l][i];
        m[0]=m0r; m[1]=m0i; m[2]=m1r; m[3]=m1i;
        m[4]=m2r; m[5]=m2i; m[6]=m3r; m[7]=m3i;
    }

    float ar[4], ai[4];
    {
        ushort4 uv = ((const ushort4*)xqb)[(size_t)wid * 256 + tid];
        ar[0] = bf2f(uv.x); ar[1] = bf2f(uv.y);
        ar[2] = bf2f(uv.z); ar[3] = bf2f(uv.w);
    }
    float ss = ar[0]*ar[0] + ar[1]*ar[1] + ar[2]*ar[2] + ar[3]*ar[3];
    #pragma unroll
    for (int off = 32; off; off >>= 1) ss += __shfl_xor(ss, off, 64);
    if (ln == 0) red[wv] = ss;
    __syncthreads();     // also covers lmat writes
    {
        float scl = 1.f / (sqrtf(red[0] + red[1] + red[2] + red[3]) + EPSN);
        #pragma unroll
        for (int r = 0; r < 4; ++r) { ar[r] *= scl; ai[r] = 0.f; }
    }

    auto lo_gates = [&](const float (*M)[8]) {
        rgate(ar, ai, M[9], 1);
        rgate(ar, ai, M[8], 2);
        bfly<1>(ar, ai, M[7], ln);
        bfly<2>(ar, ai, M[6], ln);
        bfly<4>(ar, ai, M[5], ln);
        bfly<8>(ar, ai, M[4], ln);
        bfly<16>(ar, ai, M[3], ln);
        bfly<32>(ar, ai, M[2], ln);
    };
    auto hi_gates = [&](const float (*M)[8]) {
        #pragma unroll
        for (int s = 0; s < 4; ++s) {
            int a = (wv << 8) | (ln << 2) | s;
            bufA[a ^ ((a >> 4) & 0xF)] = make_float2(ar[s], ai[s]);
        }
        __syncthreads();
        #pragma unroll
        for (int s = 0; s < 4; ++s) {
            int a = (s << 8) | (ln << 2) | wv;
            float2 v = bufA[a ^ ((a >> 4) & 0xF)];
            ar[s] = v.x; ai[s] = v.y;
        }
        rgate(ar, ai, M[1], 1);
        rgate(ar, ai, M[0], 2);
    };
    auto perm_back = [&]() {
        #pragma unroll
        for (int s = 0; s < 4; ++s) {
            int a = (s << 8) | (ln << 2) | wv;
            bufB[a ^ ((a >> 5) & 0xF)] = make_float2(ar[s], ai[s]);
        }
        __syncthreads();
        #pragma unroll
        for (int s = 0; s < 4; ++s) {
            int j = (wv << 8) | (ln << 2) | s;
            int k = (j ^ (j >> 1)) ^ ((j & 1) ? 0x300 : 0);
            float2 v = bufB[k ^ ((k >> 5) & 0xF)];
            ar[s] = v.x; ai[s] = v.y;
        }
    };

    #pragma unroll
    for (int l = 0; l < DEPTH; ++l) {
        lo_gates(lmat[l]);
        hi_gates(lmat[l]);
        perm_back();
    }
    lo_gates(lmat[DEPTH]);
    hi_gates(lmat[DEPTH]);

    #pragma unroll
    for (int s = 0; s < 4; ++s) {
        int a = (s << 8) | (ln << 2) | wv;
        bufB[a ^ ((a >> 5) & 0xF)].x = ar[s]*ar[s] + ai[s]*ai[s];
    }
    __syncthreads();
    {
        ushort4 o;
        int j0 = tid << 2;
        int a0 = (j0 + 0), a1 = (j0 + 1), a2 = (j0 + 2), a3 = (j0 + 3);
        o.x = f2bf(bufB[a0 ^ ((a0 >> 5) & 0xF)].x);
        o.y = f2bf(bufB[a1 ^ ((a1 >> 5) & 0xF)].x);
        o.z = f2bf(bufB[a2 ^ ((a2 >> 5) & 0xF)].x);
        o.w = f2bf(bufB[a3 ^ ((a3 >> 5) & 0xF)].x);
        ((ushort4*)(probs + (size_t)wid * QDIM))[tid] = o;
    }
}

// ---------------------------------------------------------------------------
// ws layout (stream-ordered reuse):
//   [ 0, 8)MB : xqb (gemm1 out, quantum in)  -> cpart z=0@0MB, z=1@4MB
//   [ 8,16)MB : probsb (quantum out, gemm2 A)
//   [16,24)MB : wb1 (gemm1 B, dead after)    -> cpart z=2@16MB, z=3@20MB
//   [24,32)MB : wb2 (gemm2 B)
//   [32,34)MB : xsb ; 34MB+: angb
// ---------------------------------------------------------------------------
extern "C" void kernel_launch(void* const* d_in, const int* in_sizes, int n_in,
                              void* d_out, int out_size, void* d_ws, size_t ws_size,
                              hipStream_t stream)
{
    const float* x          = (const float*)d_in[0];
    const float* inp_scale  = (const float*)d_in[1];
    const float* proj_in_w  = (const float*)d_in[2];
    const float* proj_in_b  = (const float*)d_in[3];
    const float* reup_w     = (const float*)d_in[4];
    const float* reup_b     = (const float*)d_in[5];
    const float* q_weights  = (const float*)d_in[6];
    const float* upl_scales = (const float*)d_in[7];
    const float* meas_w     = (const float*)d_in[8];
    const float* proj_out_w = (const float*)d_in[9];
    const float* proj_out_b = (const float*)d_in[10];
    float* out = (float*)d_out;

    char* ws = (char*)d_ws;
    unsigned short* xqb    = (unsigned short*)ws;
    float*          cpart  = (float*)ws;
    unsigned short* probsb = (unsigned short*)(ws + ((size_t) 8 << 20));
    unsigned short* wb1    = (unsigned short*)(ws + ((size_t)16 << 20));
    unsigned short* wb2    = (unsigned short*)(ws + ((size_t)24 << 20));
    unsigned short* xsb    = (unsigned short*)(ws + ((size_t)32 << 20));
    float*          angb   = (float*)(ws + ((size_t)34 << 20));

    // casts + reup in one launch
    prep_kernel<<<5632, 256, 0, stream>>>(x, inp_scale, proj_in_w, proj_out_w,
                                          reup_w, reup_b, xsb, wb1, wb2, angb);
    // xq(bf16) = xsb @ wb1^T + b   (1024 x 4096 x 1024), 64x128 tile, XCD-swz
    gemm_bt_bf16<64, 128, 128, true><<<dim3(32, 16, 1), 256, 0, stream>>>(
        xsb, wb1, proj_in_b, xqb, BB, GG * QDIM, INN, INN);
    // quantum sim -> probs (bf16), scalar version (R6)
    quantum_kernel<<<BB * GG, 256, 0, stream>>>(xqb, angb, q_weights,
                                                upl_scales, meas_w, probsb);
    // partial[z] = probs @ wb2^T  (split-K=4), 128x64 tile, XCD-swz
    gemm_bt_bf16<128, 64, 128, false><<<dim3(16, 8, 4), 256, 0, stream>>>(
        probsb, wb2, nullptr, cpart, BB, OUTN, GG * QDIM, GG * QDIM / 4);
    // out = sum partials + bias
    reduce4_kernel<<<1024, 256, 0, stream>>>(cpart, proj_out_b, out);
}

// Round 10
// 195.288 us; speedup vs baseline: 1.0850x; 1.0469x over previous
//
#include <hip/hip_runtime.h>
#include <hip/hip_bf16.h>
#include <math.h>

// Problem constants
#define BB    1024
#define INN   1024
#define OUTN  1024
#define NQ    10
#define GG    4
#define DEPTH 4
#define QDIM  1024   // 2^NQ
#define EPSN  1e-9f

typedef short  bf16x8 __attribute__((ext_vector_type(8)));
typedef float  f32x4  __attribute__((ext_vector_type(4)));

#define GLOAD_LDS16(gp, lp) __builtin_amdgcn_global_load_lds( \
    (__attribute__((address_space(1))) const void*)(gp),      \
    (__attribute__((address_space(3))) void*)(lp), 16, 0, 0)

__device__ __forceinline__ unsigned short f2bf(float f) {
    unsigned int u = __float_as_uint(f);
    u = (u + 0x7FFFu + ((u >> 16) & 1u)) >> 16;   // RNE, finite inputs
    return (unsigned short)u;
}
__device__ __forceinline__ float bf2f(unsigned short u) {
    return __uint_as_float(((unsigned int)u) << 16);
}

// DPP quad-perm lane exchange (VALU pipe)
template<int CTRL>
__device__ __forceinline__ float dppx(float x) {
    return __uint_as_float((unsigned)__builtin_amdgcn_update_dpp(
        0, (int)__float_as_uint(x), CTRL, 0xF, 0xF, true));
}

struct cplx { float r, i; };
__device__ __forceinline__ cplx cmul(cplx a, cplx b) {
    return { a.r * b.r - a.i * b.i, a.r * b.i + a.i * b.r };
}
// lmat entry layout: [br*4 + bc*2] = re, +1 = im  (2x2 complex matrix)
__device__ __forceinline__ cplx mat2(const float* __restrict__ m, int br, int bc) {
    return { m[br * 4 + bc * 2], m[br * 4 + bc * 2 + 1] };
}

// Build MFMA A-fragments for U = Ma(x)Mb(x)Mc(x)Md (16x16 complex kron).
// A1 = [Re(U) | -Im(U)], A2 = [Im(U) | Re(U)] packed along K=32.
// Lane role: r = lane&15 (row), ko = lane>>4 (k-octet: 0,1 -> first half).
__device__ __forceinline__ void build_kron(
    const float* __restrict__ Ma, const float* __restrict__ Mb,
    const float* __restrict__ Mc, const float* __restrict__ Md,
    int r, int ko, bf16x8& a1, bf16x8& a2)
{
    const int b3 = (r >> 3) & 1, b2 = (r >> 2) & 1, b1 = (r >> 1) & 1, b0 = r & 1;
    cplx za = mat2(Ma, b3, ko & 1);          // col MSB = ko&1
    cplx z01[2], z23[4];
    z01[0] = cmul(za, mat2(Mb, b2, 0));
    z01[1] = cmul(za, mat2(Mb, b2, 1));
    #pragma unroll
    for (int t2 = 0; t2 < 4; ++t2)
        z23[t2] = cmul(mat2(Mc, b1, t2 >> 1), mat2(Md, b0, t2 & 1));
    const bool hi = (ko >= 2);
    #pragma unroll
    for (int t = 0; t < 8; ++t) {
        cplx u = cmul(z01[t >> 2], z23[t & 3]);
        a1[t] = (short)f2bf(hi ? -u.i : u.r);
        a2[t] = (short)f2bf(hi ?  u.r : u.i);
    }
}

// ---------------------------------------------------------------------------
// Fused prep: [0,512): xsb = bf16(x*sc); [512,2560): wb1 = bf16(proj_in_w);
// [2560,4608): wb2 = bf16(proj_out_w); [4608,5632): reup angles.
// ---------------------------------------------------------------------------
__global__ __launch_bounds__(256) void prep_kernel(
    const float* __restrict__ x, const float* __restrict__ sc,
    const float* __restrict__ piw, const float* __restrict__ pow_,
    const float* __restrict__ rw, const float* __restrict__ rb,
    unsigned short* __restrict__ xsb, unsigned short* __restrict__ wb1,
    unsigned short* __restrict__ wb2, float* __restrict__ ang)
{
    const int bid = blockIdx.x;
    if (bid < 4608) {
        const float* src; unsigned short* dst; int i; bool scale = false;
        if (bid < 512)        { src = x;    dst = xsb; i = bid * 256 + threadIdx.x; scale = true; }
        else if (bid < 2560)  { src = piw;  dst = wb1; i = (bid - 512) * 256 + threadIdx.x; }
        else                  { src = pow_; dst = wb2; i = (bid - 2560) * 256 + threadIdx.x; }
        float4 a = ((const float4*)src)[2 * i];
        float4 b = ((const float4*)src)[2 * i + 1];
        if (scale) {
            int c4 = (2 * i) & 255;
            float4 s0 = ((const float4*)sc)[c4];
            float4 s1 = ((const float4*)sc)[c4 + 1];
            a.x *= s0.x; a.y *= s0.y; a.z *= s0.z; a.w *= s0.w;
            b.x *= s1.x; b.y *= s1.y; b.z *= s1.z; b.w *= s1.w;
        }
        ushort4 o0, o1;
        o0.x = f2bf(a.x); o0.y = f2bf(a.y); o0.z = f2bf(a.z); o0.w = f2bf(a.w);
        o1.x = f2bf(b.x); o1.y = f2bf(b.y); o1.z = f2bf(b.z); o1.w = f2bf(b.w);
        ((ushort4*)dst)[2 * i]     = o0;
        ((ushort4*)dst)[2 * i + 1] = o1;
    } else {
        const int b = bid - 4608;
        const int lane = threadIdx.x & 63;
        const int wv = threadIdx.x >> 6;
        const float* xrow = x + (size_t)b * INN;
        float xr[16];
        #pragma unroll
        for (int t = 0; t < 16; ++t) xr[t] = xrow[lane + 64 * t] * sc[lane + 64 * t];
        for (int j = wv; j < NQ * GG; j += 4) {
            const float* wrow = rw + (size_t)j * INN;
            float s = 0.f;
            #pragma unroll
            for (int t = 0; t < 16; ++t) s += xr[t] * wrow[lane + 64 * t];
            #pragma unroll
            for (int off = 32; off; off >>= 1) s += __shfl_xor(s, off, 64);
            if (lane == 0) {
                float a = tanhf(s + rb[j]) * 3.14159265358979323846f;
                int g = j / NQ, i = j % NQ;
                ang[((size_t)b * GG + g) * NQ + i] = a;
            }
        }
    }
}

// ---------------------------------------------------------------------------
// bf16 MFMA GEMM (unchanged from R9): 4 waves, BK=128, XOR-swizzled LDS,
// XCD-aware bijective block swizzle, split-K via z.
// ---------------------------------------------------------------------------
template<int BM, int BN, int BK, bool OUTBF>
__global__ __launch_bounds__(256) void gemm_bt_bf16(
    const unsigned short* __restrict__ A, const unsigned short* __restrict__ Bw,
    const float* __restrict__ bias, void* __restrict__ Cv,
    int M, int N, int K, int KC)
{
    static_assert(BK == 128, "swizzle assumes BK=128");
    constexpr int WM = BM / 2, WN = BN / 2;
    constexpr int FM = WM / 16, FN = WN / 16;
    constexpr int KS = BK / 32;
    constexpr int NA = (BM * BK) / 2048;
    constexpr int NB = (BN * BK) / 2048;

    __shared__ unsigned short As[BM * BK];
    __shared__ unsigned short Bs[BN * BK];

    const int nx = gridDim.x, ny = gridDim.y;
    const int nwg = nx * ny * gridDim.z;
    const int lin = blockIdx.x + nx * (blockIdx.y + ny * blockIdx.z);
    const int nl  = (lin & 7) * (nwg >> 3) + (lin >> 3);
    const int by  = nl % ny;
    const int bx  = (nl / ny) % nx;
    const int bz  = nl / (ny * nx);

    const int tid  = threadIdx.x;
    const int lane = tid & 63;
    const int wave = tid >> 6;
    const int wm = wave >> 1, wn = wave & 1;
    const int m0 = by * BM;
    const int n0 = bx * BN;
    const int k0 = bz * KC;

    const int cl = lane & 15;
    const int rh = lane >> 4;

    f32x4 acc[FM][FN];
    #pragma unroll
    for (int i = 0; i < FM; ++i)
        #pragma unroll
        for (int j = 0; j < FN; ++j)
            acc[i][j] = (f32x4){0.f, 0.f, 0.f, 0.f};

    for (int kt = k0; kt < k0 + KC; kt += BK) {
        #pragma unroll
        for (int q = 0; q < NA; ++q) {
            int eo  = q * 2048 + tid * 8;
            int row = eo >> 7;
            int pb  = (eo & 127) >> 3;
            int gb  = pb ^ (row & 7);
            GLOAD_LDS16(A + (size_t)(m0 + row) * K + kt + gb * 8, &As[eo]);
        }
        #pragma unroll
        for (int q = 0; q < NB; ++q) {
            int eo  = q * 2048 + tid * 8;
            int row = eo >> 7;
            int pb  = (eo & 127) >> 3;
            int gb  = pb ^ (row & 7);
            GLOAD_LDS16(Bw + (size_t)(n0 + row) * K + kt + gb * 8, &Bs[eo]);
        }
        __syncthreads();

        #pragma unroll
        for (int ks = 0; ks < KS; ++ks) {
            bf16x8 af[FM], bfr[FN];
            #pragma unroll
            for (int mi = 0; mi < FM; ++mi) {
                int row = wm * WM + mi * 16 + cl;
                int pb  = (ks * 4 + rh) ^ (row & 7);
                af[mi] = *(const bf16x8*)&As[row * BK + pb * 8];
            }
            #pragma unroll
            for (int ni = 0; ni < FN; ++ni) {
                int row = wn * WN + ni * 16 + cl;
                int pb  = (ks * 4 + rh) ^ (row & 7);
                bfr[ni] = *(const bf16x8*)&Bs[row * BK + pb * 8];
            }
            #pragma unroll
            for (int mi = 0; mi < FM; ++mi)
                #pragma unroll
                for (int ni = 0; ni < FN; ++ni)
                    acc[mi][ni] = __builtin_amdgcn_mfma_f32_16x16x32_bf16(
                        af[mi], bfr[ni], acc[mi][ni], 0, 0, 0);
        }
        __syncthreads();
    }

    const size_t pofs = OUTBF ? 0 :
        ((size_t)(bz & 1) + ((size_t)(bz >> 1) << 2)) * ((size_t)M * N);
    #pragma unroll
    for (int mi = 0; mi < FM; ++mi) {
        #pragma unroll
        for (int ni = 0; ni < FN; ++ni) {
            int gm = m0 + wm * WM + mi * 16 + rh * 4;
            int gn = n0 + wn * WN + ni * 16 + cl;
            float bsv = bias ? bias[gn] : 0.f;
            #pragma unroll
            for (int j = 0; j < 4; ++j) {
                float val = acc[mi][ni][j] + bsv;
                if (OUTBF)
                    ((unsigned short*)Cv)[(size_t)(gm + j) * N + gn] = f2bf(val);
                else
                    ((float*)Cv)[pofs + (size_t)(gm + j) * N + gn] = val;
            }
        }
    }
}

// out = p0 + p1 + p2 + p3 + bias
__global__ __launch_bounds__(256) void reduce4_kernel(
    const float* __restrict__ p, const float* __restrict__ bias,
    float* __restrict__ out)
{
    int i = blockIdx.x * 256 + threadIdx.x;
    float4 a = ((const float4*)p)[i];
    float4 b = ((const float4*)p)[i + (1 << 18)];
    float4 c = ((const float4*)p)[i + (1 << 20)];
    float4 d = ((const float4*)p)[i + (1 << 20) + (1 << 18)];
    float4 bv = ((const float4*)bias)[i & 255];
    float4 o;
    o.x = a.x + b.x + c.x + d.x + bv.x;
    o.y = a.y + b.y + c.y + d.y + bv.y;
    o.z = a.z + b.z + c.z + d.z + bv.z;
    o.w = a.w + b.w + c.w + d.w + bv.w;
    ((float4*)out)[i] = o;
}

// ---------------------------------------------------------------------------
// Quantum statevector sim on MATRIX CORES. One state per WAVE (4 states/block).
// State = 16x64 complex matrix: rows = amp bits 9:6, cols = bits 5:0.
// Per layer: phase1 = wires0-3 (bits9:6) as U(16x16) x S via 8 bf16 MFMAs
// ([R|-I],[I|R] K=32 packing); LDS relayout to T[p=bits5:2][q=(bits9:6,bits1:0)];
// phase2 = wires4-7 likewise; phase3 = wires8-9 as 4x4 complex gate across
// DPP quad lanes, fused with CNOT-chain perm via inverse-perm table, scattered
// back to B-ready LDS layout. Wave-local => zero block barriers in main loop.
// SB layout: u16[64 cols][32] with k = reim*16 + row (B-fragment-ready).
// ---------------------------------------------------------------------------
__global__ __launch_bounds__(256) void quantum_mfma(
    const unsigned short* __restrict__ xqb, const float* __restrict__ ang,
    const float* __restrict__ qw, const float* __restrict__ us,
    const float* __restrict__ mw, unsigned short* __restrict__ probs)
{
    __shared__ unsigned short SB[4][2048];            // 4 KB per wave
    __shared__ float lmat[4][DEPTH + 1][NQ][8];       // per-wave gate matrices
    __shared__ unsigned short inv[QDIM];              // inverse CNOT perm (shared)

    const int tid = threadIdx.x;
    const int wv  = tid >> 6, ln = tid & 63;
    const int wid = blockIdx.x * 4 + wv;              // state id
    const int g   = wid & 3;
    const int cl  = ln & 15, ko = ln >> 4;

    // ---- inverse permutation table: inv[k(j)] = j,  k(j)=(j^(j>>1))^((j&1)?0x300:0)
    #pragma unroll
    for (int s = 0; s < 4; ++s) {
        int j = tid * 4 + s;
        int k = ((j ^ (j >> 1)) ^ ((j & 1) ? 0x300 : 0)) & 1023;
        inv[k] = (unsigned short)j;
    }

    // ---- build 50 fused gate matrices for this wave's state (lanes 0..49)
    if (ln < (DEPTH + 1) * NQ) {
        const int l = ln / NQ;
        const int i = ln - l * NQ;
        float carry = 0.f;
        if (l > 0) {
            int pl = (l == DEPTH) ? DEPTH - 1 : l - 1;
            carry = qw[(((size_t)g * DEPTH + pl) * NQ + i) * 3 + 2];
        }
        float m0r,m0i,m1r,m1i,m2r,m2i,m3r,m3i;
        if (l < DEPTH) {
            int idx = (g * DEPTH + l) * NQ + i;
            float q0 = qw[(size_t)idx * 3 + 0], q1 = qw[(size_t)idx * 3 + 1];
            float beta = ang[(size_t)wid * NQ + i] * us[idx] + carry;
            float s0 = sinf(0.5f * q0), c0 = cosf(0.5f * q0);
            float s1 = sinf(0.5f * q1), c1 = cosf(0.5f * q1);
            float p0r =  c1 * c0, p0i =  s1 * s0;
            float p1r = -s1 * c0, p1i = -c1 * s0;
            float p2r =  s1 * c0, p2i = -c1 * s0;
            float p3r =  c1 * c0, p3i = -s1 * s0;
            float cb = cosf(0.5f * beta), sb2 = sinf(0.5f * beta);
            m0r = p0r*cb + p1r*sb2;  m0i = p0i*cb + p1i*sb2;
            m1r = p1r*cb - p0r*sb2;  m1i = p1i*cb - p0i*sb2;
            m2r = p2r*cb + p3r*sb2;  m2i = p2i*cb + p3i*sb2;
            m3r = p3r*cb - p2r*sb2;  m3i = p3i*cb - p2i*sb2;
        } else {
            const float* q = mw + ((size_t)g * NQ + i) * 3;
            float th = q[0], ph = q[1], lm_ = q[2];
            float c = cosf(0.5f * th), s = sinf(0.5f * th);
            float epr = cosf(ph), epi = sinf(ph);
            float elr = cosf(lm_), eli = sinf(lm_);
            float u0r = c,        u0i = 0.f;
            float u1r = -elr * s, u1i = -eli * s;
            float u2r = epr * s,  u2i = epi * s;
            float u3r = (epr*elr - epi*eli) * c;
            float u3i = (epr*eli + epi*elr) * c;
            float cc = cosf(0.5f * carry), sc2 = sinf(0.5f * carry);
            m0r = u0r*cc + u1r*sc2;  m0i = u0i*cc + u1i*sc2;
            m1r = u1r*cc - u0r*sc2;  m1i = u1i*cc - u0i*sc2;
            m2r = u2r*cc + u3r*sc2;  m2i = u2i*cc + u3i*sc2;
            m3r = u3r*cc - u2r*sc2;  m3i = u3i*cc - u2i*sc2;
        }
        float* m = lmat[wv][l][i];
        m[0]=m0r; m[1]=m0i; m[2]=m1r; m[3]=m1i;
        m[4]=m2r; m[5]=m2i; m[6]=m3r; m[7]=m3i;
    }

    // ---- load amps (16/lane), wave-norm, fill SB (scaled) ----
    unsigned short* sb = SB[wv];
    {
        const unsigned short* src = xqb + (size_t)wid * QDIM + ln * 16;
        bf16x8 r0 = *(const bf16x8*)src;
        bf16x8 r1 = *(const bf16x8*)(src + 8);
        float v[16]; float ss = 0.f;
        #pragma unroll
        for (int t = 0; t < 8; ++t) { v[t] = bf2f((unsigned short)r0[t]); ss += v[t]*v[t]; }
        #pragma unroll
        for (int t = 0; t < 8; ++t) { v[8+t] = bf2f((unsigned short)r1[t]); ss += v[8+t]*v[8+t]; }
        #pragma unroll
        for (int off = 32; off; off >>= 1) ss += __shfl_xor(ss, off, 64);
        float scl = 1.f / (sqrtf(ss) + EPSN);
        #pragma unroll
        for (int t = 0; t < 16; ++t) {
            int a = ln * 16 + t;
            int c = a & 63, rr = a >> 6;
            sb[c * 32 + rr]      = f2bf(v[t] * scl);
            sb[c * 32 + 16 + rr] = 0;
        }
    }
    __syncthreads();   // inv table visible to all waves

    const f32x4 fz = (f32x4){0.f, 0.f, 0.f, 0.f};

    for (int l = 0; l <= DEPTH; ++l) {
        const float (*Mw)[8] = lmat[wv][l];

        // ---- phase 1: wires 0-3 (amp bits 9:6) ----
        bf16x8 A1, A2;
        build_kron(Mw[0], Mw[1], Mw[2], Mw[3], cl, ko, A1, A2);
        f32x4 Dr[4], Di[4];
        #pragma unroll
        for (int ct = 0; ct < 4; ++ct) {
            bf16x8 bf = *(const bf16x8*)&sb[(ct * 16 + cl) * 32 + ko * 8];
            Dr[ct] = __builtin_amdgcn_mfma_f32_16x16x32_bf16(A1, bf, fz, 0, 0, 0);
            Di[ct] = __builtin_amdgcn_mfma_f32_16x16x32_bf16(A2, bf, fz, 0, 0, 0);
        }

        // ---- relayout D -> T[p][q] in sb (same-wave in-order DS: safe) ----
        #pragma unroll
        for (int ct = 0; ct < 4; ++ct) {
            int c = ct * 16 + cl;
            int p = c >> 2, lo = c & 3;
            #pragma unroll
            for (int jj = 0; jj < 4; ++jj) {
                int q = ((ko * 4 + jj) << 2) | lo;
                sb[q * 32 + p]      = f2bf(Dr[ct][jj]);
                sb[q * 32 + 16 + p] = f2bf(Di[ct][jj]);
            }
        }

        // ---- phase 2: wires 4-7 (amp bits 5:2) ----
        build_kron(Mw[4], Mw[5], Mw[6], Mw[7], cl, ko, A1, A2);
        f32x4 Er[4], Ei[4];
        #pragma unroll
        for (int ct = 0; ct < 4; ++ct) {
            bf16x8 bf = *(const bf16x8*)&sb[(ct * 16 + cl) * 32 + ko * 8];
            Er[ct] = __builtin_amdgcn_mfma_f32_16x16x32_bf16(A1, bf, fz, 0, 0, 0);
            Ei[ct] = __builtin_amdgcn_mfma_f32_16x16x32_bf16(A2, bf, fz, 0, 0, 0);
        }

        // ---- phase 3: wires 8-9 (amp bits 1:0) via DPP quad rotate + perm-scatter
        const int lo3 = ln & 3, l1b = lo3 >> 1, l0b = lo3 & 1;
        cplx C0, C1, C2, C3;
        {
            int lp0 = lo3, lp1 = (lo3 + 1) & 3, lp2 = (lo3 + 2) & 3, lp3 = (lo3 + 3) & 3;
            C0 = cmul(mat2(Mw[8], l1b, lp0 >> 1), mat2(Mw[9], l0b, lp0 & 1));
            C1 = cmul(mat2(Mw[8], l1b, lp1 >> 1), mat2(Mw[9], l0b, lp1 & 1));
            C2 = cmul(mat2(Mw[8], l1b, lp2 >> 1), mat2(Mw[9], l0b, lp2 & 1));
            C3 = cmul(mat2(Mw[8], l1b, lp3 >> 1), mat2(Mw[9], l0b, lp3 & 1));
        }
        #pragma unroll
        for (int ct = 0; ct < 4; ++ct) {
            int q = ct * 16 + cl;
            int abase = ((q >> 2) << 6) | (q & 3);
            #pragma unroll
            for (int jj = 0; jj < 4; ++jj) {
                float vr = Er[ct][jj], vi = Ei[ct][jj];
                float t1r = dppx<0x39>(vr), t1i = dppx<0x39>(vi);   // v[(lo+1)&3]
                float t2r = dppx<0x4E>(vr), t2i = dppx<0x4E>(vi);   // v[(lo+2)&3]
                float t3r = dppx<0x93>(vr), t3i = dppx<0x93>(vi);   // v[(lo+3)&3]
                float outr = C0.r*vr - C0.i*vi + C1.r*t1r - C1.i*t1i
                           + C2.r*t2r - C2.i*t2i + C3.r*t3r - C3.i*t3i;
                float outi = C0.r*vi + C0.i*vr + C1.r*t1i + C1.i*t1r
                           + C2.r*t2i + C2.i*t2r + C3.r*t3i + C3.i*t3r;
                int a = abase | ((ko * 4 + jj) << 2);
                if (l < DEPTH) {
                    int j = inv[a];                    // fused CNOT-chain perm
                    sb[(j & 63) * 32 + (j >> 6)]      = f2bf(outr);
                    sb[(j & 63) * 32 + 16 + (j >> 6)] = f2bf(outi);
                } else {
                    sb[a] = f2bf(outr * outr + outi * outi);   // probs (bf16)
                }
            }
        }
    }

    // ---- coalesced probs writeback from sb[0..1023] ----
    {
        bf16x8 p0 = *(const bf16x8*)&sb[ln * 16];
        bf16x8 p1 = *(const bf16x8*)&sb[ln * 16 + 8];
        unsigned short* dst = probs + (size_t)wid * QDIM + ln * 16;
        *(bf16x8*)dst       = p0;
        *(bf16x8*)(dst + 8) = p1;
    }
}

// ---------------------------------------------------------------------------
// ws layout (stream-ordered reuse):
//   [ 0, 8)MB : xqb (gemm1 out, quantum in)  -> cpart z=0@0MB, z=1@4MB
//   [ 8,16)MB : probsb (quantum out, gemm2 A)
//   [16,24)MB : wb1 (gemm1 B, dead after)    -> cpart z=2@16MB, z=3@20MB
//   [24,32)MB : wb2 (gemm2 B)
//   [32,34)MB : xsb ; 34MB+: angb
// ---------------------------------------------------------------------------
extern "C" void kernel_launch(void* const* d_in, const int* in_sizes, int n_in,
                              void* d_out, int out_size, void* d_ws, size_t ws_size,
                              hipStream_t stream)
{
    const float* x          = (const float*)d_in[0];
    const float* inp_scale  = (const float*)d_in[1];
    const float* proj_in_w  = (const float*)d_in[2];
    const float* proj_in_b  = (const float*)d_in[3];
    const float* reup_w     = (const float*)d_in[4];
    const float* reup_b     = (const float*)d_in[5];
    const float* q_weights  = (const float*)d_in[6];
    const float* upl_scales = (const float*)d_in[7];
    const float* meas_w     = (const float*)d_in[8];
    const float* proj_out_w = (const float*)d_in[9];
    const float* proj_out_b = (const float*)d_in[10];
    float* out = (float*)d_out;

    char* ws = (char*)d_ws;
    unsigned short* xqb    = (unsigned short*)ws;
    float*          cpart  = (float*)ws;
    unsigned short* probsb = (unsigned short*)(ws + ((size_t) 8 << 20));
    unsigned short* wb1    = (unsigned short*)(ws + ((size_t)16 << 20));
    unsigned short* wb2    = (unsigned short*)(ws + ((size_t)24 << 20));
    unsigned short* xsb    = (unsigned short*)(ws + ((size_t)32 << 20));
    float*          angb   = (float*)(ws + ((size_t)34 << 20));

    // casts + reup in one launch
    prep_kernel<<<5632, 256, 0, stream>>>(x, inp_scale, proj_in_w, proj_out_w,
                                          reup_w, reup_b, xsb, wb1, wb2, angb);
    // xq(bf16) = xsb @ wb1^T + b   (1024 x 4096 x 1024)
    gemm_bt_bf16<64, 128, 128, true><<<dim3(32, 16, 1), 256, 0, stream>>>(
        xsb, wb1, proj_in_b, xqb, BB, GG * QDIM, INN, INN);
    // quantum sim on matrix cores -> probs (bf16); one state per wave
    quantum_mfma<<<BB * GG / 4, 256, 0, stream>>>(xqb, angb, q_weights,
                                                  upl_scales, meas_w, probsb);
    // partial[z] = probs @ wb2^T  (split-K=4)
    gemm_bt_bf16<128, 64, 128, false><<<dim3(16, 8, 4), 256, 0, stream>>>(
        probsb, wb2, nullptr, cpart, BB, OUTN, GG * QDIM, GG * QDIM / 4);
    // out = sum partials + bias
    reduce4_kernel<<<1024, 256, 0, stream>>>(cpart, proj_out_b, out);
}